// Round 12
// baseline (32152.512 us; speedup 1.0000x reference)
//
#include <hip/hip_runtime.h>
#include <hip/hip_bf16.h>
#include <stdint.h>

// ---------------- types ----------------
using bfrag_t = __attribute__((ext_vector_type(8))) short;   // 8 bf16 (4 VGPRs)
using f32x16  = __attribute__((ext_vector_type(16))) float;  // 32x32 MFMA acc

#define HID  512
#define H3   256
#define RB   128      // batch rows per block (RB=64 / NTH=1024 / fused-L4 all measured: FETCH blowup)
#define NTH  512      // 8 waves — R1 structure, best measured (21859 us)
#define KSC  2.885390081777927f   // 2*log2(e): tanh(x) = 1 - 2/(exp2(KSC*x)+1)

static __device__ __forceinline__ uint32_t bf16_rne(float f) {
    uint32_t u = __float_as_uint(f);
    return (u + 0x7fffu + ((u >> 16) & 1u)) >> 16;
}
static __device__ __forceinline__ uint32_t pk_bf16(float a, float b) {
    union { __hip_bfloat162 h; uint32_t u; } c;
    c.h = __float22bfloat162_rn(make_float2(a, b));   // v_cvt_pk_bf16_f32 on gfx950
    return c.u;
}
static __device__ __forceinline__ float fast_exp2(float x) {
#if __has_builtin(__builtin_amdgcn_exp2f)
    return __builtin_amdgcn_exp2f(x);
#else
    return exp2f(x);
#endif
}
static __device__ __forceinline__ float fast_rcp(float x) {
#if __has_builtin(__builtin_amdgcn_rcpf)
    return __builtin_amdgcn_rcpf(x);
#else
    return 1.0f / x;
#endif
}
// input is PRE-SCALED by KSC (weights/biases scaled in prep)
static __device__ __forceinline__ float ftanh_s(float xs) {
    float e = fast_exp2(xs);
    return 1.0f - 2.0f * fast_rcp(e + 1.0f);
}
static __device__ __forceinline__ bfrag_t frag_of(uint4 v) {
    union { uint4 u; bfrag_t f; } c; c.u = v; return c.f;
}

// ---------------- prep: swizzle W2^T / W3^T (scaled by KSC) into 32x32x16 MFMA
// A-frag order; also emit scaled W1-pack [ck][w0*8|w1*8|b*8] and scaled b2/b3. ----
// A-frag layout (32x32x16 bf16): lane l -> m = l&31, k = kt*16 + (l>>5)*8 + j (j=0..7,
// packed as 4 dwords of (even,odd) bf16 pairs). Index: [(mt32*32 + kt)*64 + l].
__global__ void prep_weights(const float* __restrict__ W1, const float* __restrict__ b1,
                             const float* __restrict__ W2, const float* __restrict__ b2,
                             const float* __restrict__ W3, const float* __restrict__ b3,
                             uint4* __restrict__ o2, uint4* __restrict__ o3,
                             float* __restrict__ w1p, float* __restrict__ b2s,
                             float* __restrict__ b3s)
{
    int id = blockIdx.x * 256 + threadIdx.x;
    if (id < 32768) {                       // W2: 16 mt32 * 32 kt * 64 lanes
        int l = id & 63, kt = (id >> 6) & 31, mt = id >> 11;
        int m = mt * 32 + (l & 31), k0 = kt * 16 + (l >> 5) * 8;
        uint32_t p[4];
        #pragma unroll
        for (int jj = 0; jj < 4; ++jj) {
            float v0 = KSC * W2[(k0 + jj * 2    ) * 512 + m];  // W2^T[m][k] = W2[k][m]
            float v1 = KSC * W2[(k0 + jj * 2 + 1) * 512 + m];
            p[jj] = bf16_rne(v0) | (bf16_rne(v1) << 16);
        }
        o2[id] = make_uint4(p[0], p[1], p[2], p[3]);
    } else if (id < 49152) {                // W3: 8 mt32 * 32 kt * 64 lanes
        int id2 = id - 32768;
        int l = id2 & 63, kt = (id2 >> 6) & 31, mt = id2 >> 11;
        int m = mt * 32 + (l & 31), k0 = kt * 16 + (l >> 5) * 8;
        uint32_t p[4];
        #pragma unroll
        for (int jj = 0; jj < 4; ++jj) {
            float v0 = KSC * W3[(k0 + jj * 2    ) * 256 + m];
            float v1 = KSC * W3[(k0 + jj * 2 + 1) * 256 + m];
            p[jj] = bf16_rne(v0) | (bf16_rne(v1) << 16);
        }
        o3[id2] = make_uint4(p[0], p[1], p[2], p[3]);
    } else if (id < 49152 + 1536) {         // W1 pack: 64 chunks x 24 floats
        int t = id - 49152;
        int ck = t / 24, j = t % 24;
        int f = ck * 8 + (j & 7);
        float v = (j < 8) ? W1[f] : (j < 16) ? W1[512 + f] : b1[f];
        w1p[t] = KSC * v;
    } else if (id < 49152 + 1536 + 512) {
        int i = id - 49152 - 1536; b2s[i] = KSC * b2[i];
    } else if (id < 49152 + 1536 + 512 + 256) {
        int i = id - 49152 - 1536 - 512; b3s[i] = KSC * b3[i];
    }
}

// ---------------- main persistent kernel ----------------
struct SmemT {
    uint4  hbuf[64 * RB];    // 128 KB: h1/h2 (512 feats) or h3 (first 32 chunks)
    float  b2[HID];          // scaled
    float  b3[H3];           // scaled
    float  y [RB][2];
    float  z [RB][2];
    float  ya[RB][2];
    float  part[4][RB][2];   // layer4 partials
};                            // 141312 B, identical to the 21859-us config

__global__ __launch_bounds__(NTH, 2) void node_kernel(
    const float* __restrict__ y0, const float* __restrict__ tp,
    const float* __restrict__ W4g, const float* __restrict__ b4g,
    const uint4* __restrict__ w2A, const uint4* __restrict__ w3A,
    const float* __restrict__ w1p, const float* __restrict__ b2s,
    const float* __restrict__ b3s,
    float* __restrict__ out, int Bn, int T)
{
    __shared__ SmemT s;
    const int tid = threadIdx.x;
    const int l   = tid & 63;
    const int w   = tid >> 6;                                  // wave 0..7
    const int wu  = __builtin_amdgcn_readfirstlane(w);         // provably uniform
    const int b0  = blockIdx.x * RB;
    const int ln  = l & 31, lh = l >> 5;

    // stage biases (scaled) to LDS; init y/z/ya; write trajectory[0]
    for (int i = tid; i < HID; i += NTH) s.b2[i] = b2s[i];
    for (int i = tid; i < H3;  i += NTH) s.b3[i] = b3s[i];
    if (tid < RB) {
        float2 v = ((const float2*)y0)[b0 + tid];
        s.y [tid][0] = v.x; s.y [tid][1] = v.y;
        s.z [tid][0] = v.x; s.z [tid][1] = v.y;
        s.ya[tid][0] = v.x; s.ya[tid][1] = v.y;
        ((float2*)out)[b0 + tid] = v;          // trajectory[0] = y0
    }
    __syncthreads();

    const float* w1w = w1p + wu * 8 * 24;      // this wave's 8 chunks (uniform)
    // per-wave weight base pointers: tile (mt,kt) at pW[mt*2048 + kt*64]
    const uint4* pW2 = w2A + (wu * 64) * 64 + l;       // mt32 = wu*2 + mt
    const int mg = wu >> 1, ng = wu & 1;
    const uint4* pW3 = w3A + (mg * 64) * 64 + l;       // mt32 = mg*2 + mt

    for (int st = 0; st < T - 1; ++st) {
        float dt = tp[st + 1] - tp[st];

        for (int e = 0; e < 4; ++e) {
            // ---- 4-deep A-frag pipeline for L2 (issue->use = 4 kt ≈ 256 cy cover);
            //      first 4 stages issued here to hide under the L1 phase ----
            uint4 aC[2], aN1[2], aN2[2], aN3[2];
            aC [0] = pW2[0];        aC [1] = pW2[2048];
            aN1[0] = pW2[64];       aN1[1] = pW2[2048 + 64];
            aN2[0] = pW2[128];      aN2[1] = pW2[2048 + 128];
            aN3[0] = pW2[192];      aN3[1] = pW2[2048 + 192];

            // ---- layer1: h1 = tanh(z @ W1 + b1); two rows per lane ----
            {
                float zl0 = s.z[l][0],      zl1 = s.z[l][1];
                float zh0 = s.z[64 + l][0], zh1 = s.z[64 + l][1];
                #pragma unroll
                for (int i = 0; i < 8; ++i) {
                    const float* P = w1w + i * 24;   // uniform -> s_load
                    int ck = wu * 8 + i;
                    float xa[8], xb[8];
                    #pragma unroll
                    for (int jj = 0; jj < 8; ++jj) {
                        float wa = P[jj], wb = P[8 + jj], bb = P[16 + jj];
                        xa[jj] = ftanh_s(fmaf(zl0, wa, fmaf(zl1, wb, bb)));
                        xb[jj] = ftanh_s(fmaf(zh0, wa, fmaf(zh1, wb, bb)));
                    }
                    s.hbuf[ck * RB + l] = make_uint4(
                        pk_bf16(xa[0], xa[1]), pk_bf16(xa[2], xa[3]),
                        pk_bf16(xa[4], xa[5]), pk_bf16(xa[6], xa[7]));
                    s.hbuf[ck * RB + 64 + l] = make_uint4(
                        pk_bf16(xb[0], xb[1]), pk_bf16(xb[2], xb[3]),
                        pk_bf16(xb[4], xb[5]), pk_bf16(xb[6], xb[7]));
                }
            }
            __syncthreads();

            // ---- layer2: h2^T = W2^T @ h1^T + b2   M=512, N=128, K=512 (32x32x16) ----
            uint4 a3C[2], a3N1[2], a3N2[2], a3N3[2];
            {
                f32x16 acc[2][4];
                #pragma unroll
                for (int mt = 0; mt < 2; ++mt) {
                    int mb = (wu * 2 + mt) * 32 + 4 * lh;
                    float bv[16];
                    *(float4*)&bv[0]  = *(const float4*)&s.b2[mb];
                    *(float4*)&bv[4]  = *(const float4*)&s.b2[mb + 8];
                    *(float4*)&bv[8]  = *(const float4*)&s.b2[mb + 16];
                    *(float4*)&bv[12] = *(const float4*)&s.b2[mb + 24];
                    f32x16 a;
                    #pragma unroll
                    for (int r = 0; r < 16; ++r) a[r] = bv[r];
                    #pragma unroll
                    for (int nt = 0; nt < 4; ++nt) acc[mt][nt] = a;
                }
                #pragma unroll 2
                for (int kt = 0; kt < 32; ++kt) {
                    uint4 bF[4];
                    #pragma unroll
                    for (int nt = 0; nt < 4; ++nt)
                        bF[nt] = s.hbuf[(kt * 2 + lh) * RB + nt * 32 + ln];
                    int kq = (kt < 28) ? (kt + 4) : 27;      // 4-deep prefetch (clamped; tail loads dead)
                    uint4 aM0 = pW2[kq * 64];
                    uint4 aM1 = pW2[2048 + kq * 64];
                    #pragma unroll
                    for (int mt = 0; mt < 2; ++mt)
                        #pragma unroll
                        for (int nt = 0; nt < 4; ++nt)
                            acc[mt][nt] = __builtin_amdgcn_mfma_f32_32x32x16_bf16(
                                frag_of(aC[mt]), frag_of(bF[nt]), acc[mt][nt], 0, 0, 0);
                    aC[0]  = aN1[0]; aC[1]  = aN1[1];
                    aN1[0] = aN2[0]; aN1[1] = aN2[1];
                    aN2[0] = aN3[0]; aN2[1] = aN3[1];
                    aN3[0] = aM0;    aN3[1] = aM1;
                }
                // prefetch L3's first four A-frag pairs (hide latency under epilogue+barrier)
                a3C [0] = pW3[0];        a3C [1] = pW3[2048];
                a3N1[0] = pW3[64];       a3N1[1] = pW3[2048 + 64];
                a3N2[0] = pW3[128];      a3N2[1] = pW3[2048 + 128];
                a3N3[0] = pW3[192];      a3N3[1] = pW3[2048 + 192];
                __syncthreads();   // all waves done reading h1
                // epilogue: tanh (pre-scaled), pack, overwrite hbuf with h2
                // C/D: col = ln (batch row), row = (r&3) + 8*(r>>2) + 4*lh
                #pragma unroll
                for (int mt = 0; mt < 2; ++mt) {
                    int m0 = (wu * 2 + mt) * 32 + 4 * lh;
                    int hi = lh;                     // (m0>>2)&1
                    #pragma unroll
                    for (int nt = 0; nt < 4; ++nt) {
                        int n = nt * 32 + ln;
                        f32x16 c = acc[mt][nt];
                        #pragma unroll
                        for (int g = 0; g < 4; ++g) {
                            int ck = (m0 + 8 * g) >> 3;
                            uint32_t u0 = pk_bf16(ftanh_s(c[4 * g    ]), ftanh_s(c[4 * g + 1]));
                            uint32_t u1 = pk_bf16(ftanh_s(c[4 * g + 2]), ftanh_s(c[4 * g + 3]));
                            ((uint2*)s.hbuf)[((ck * RB + n) << 1) | hi] = make_uint2(u0, u1);
                        }
                    }
                }
                __syncthreads();
            }

            // ---- layer3: h3^T = W3^T @ h2^T + b3   M=256, N=128, K=512 (32x32x16) ----
            {
                f32x16 acc3[2][2];
                #pragma unroll
                for (int mt = 0; mt < 2; ++mt) {
                    int mb = (mg * 2 + mt) * 32 + 4 * lh;
                    float bv[16];
                    *(float4*)&bv[0]  = *(const float4*)&s.b3[mb];
                    *(float4*)&bv[4]  = *(const float4*)&s.b3[mb + 8];
                    *(float4*)&bv[8]  = *(const float4*)&s.b3[mb + 16];
                    *(float4*)&bv[12] = *(const float4*)&s.b3[mb + 24];
                    f32x16 a;
                    #pragma unroll
                    for (int r = 0; r < 16; ++r) a[r] = bv[r];
                    #pragma unroll
                    for (int nt = 0; nt < 2; ++nt) acc3[mt][nt] = a;
                }
                #pragma unroll 2
                for (int kt = 0; kt < 32; ++kt) {
                    uint4 bF[2];
                    #pragma unroll
                    for (int nt = 0; nt < 2; ++nt)
                        bF[nt] = s.hbuf[(kt * 2 + lh) * RB + ng * 64 + nt * 32 + ln];
                    int kq = (kt < 28) ? (kt + 4) : 27;
                    uint4 aM0 = pW3[kq * 64];
                    uint4 aM1 = pW3[2048 + kq * 64];
                    #pragma unroll
                    for (int mt = 0; mt < 2; ++mt)
                        #pragma unroll
                        for (int nt = 0; nt < 2; ++nt)
                            acc3[mt][nt] = __builtin_amdgcn_mfma_f32_32x32x16_bf16(
                                frag_of(a3C[mt]), frag_of(bF[nt]), acc3[mt][nt], 0, 0, 0);
                    a3C[0]  = a3N1[0]; a3C[1]  = a3N1[1];
                    a3N1[0] = a3N2[0]; a3N1[1] = a3N2[1];
                    a3N2[0] = a3N3[0]; a3N2[1] = a3N3[1];
                    a3N3[0] = aM0;     a3N3[1] = aM1;
                }
                __syncthreads();   // all waves done reading h2
                #pragma unroll
                for (int mt = 0; mt < 2; ++mt) {
                    int m0 = (mg * 2 + mt) * 32 + 4 * lh;   // feature 0..255 -> ck 0..31
                    int hi = lh;
                    #pragma unroll
                    for (int nt = 0; nt < 2; ++nt) {
                        int n = ng * 64 + nt * 32 + ln;
                        f32x16 c = acc3[mt][nt];
                        #pragma unroll
                        for (int g = 0; g < 4; ++g) {
                            int ck = (m0 + 8 * g) >> 3;
                            uint32_t u0 = pk_bf16(ftanh_s(c[4 * g    ]), ftanh_s(c[4 * g + 1]));
                            uint32_t u1 = pk_bf16(ftanh_s(c[4 * g + 2]), ftanh_s(c[4 * g + 3]));
                            ((uint2*)s.hbuf)[((ck * RB + n) << 1) | hi] = make_uint2(u0, u1);
                        }
                    }
                }
                __syncthreads();
            }

            // ---- layer4 partials: contiguous-row reads, uniform W4 s_loads ----
            {
                int r  = tid & 127;                      // = l + 64*(w&1): contiguous
                int qq = __builtin_amdgcn_readfirstlane(tid >> 7);  // 0..3 uniform
                float a0 = 0.f, a1 = 0.f;
                #pragma unroll
                for (int j = 0; j < 8; ++j) {
                    int ck = qq * 8 + j;
                    uint4 hv = s.hbuf[ck * RB + r];
                    const uint32_t* pu = (const uint32_t*)&hv;
                    #pragma unroll
                    for (int jj = 0; jj < 4; ++jj) {
                        uint32_t uu = pu[jj];
                        float h0 = __uint_as_float(uu << 16);
                        float h1 = __uint_as_float(uu & 0xffff0000u);
                        int f = ck * 8 + jj * 2;                     // uniform
                        a0 = fmaf(h0, W4g[f * 2],     fmaf(h1, W4g[f * 2 + 2], a0));
                        a1 = fmaf(h0, W4g[f * 2 + 1], fmaf(h1, W4g[f * 2 + 3], a1));
                    }
                }
                s.part[qq][r][0] = a0; s.part[qq][r][1] = a1;
            }
            __syncthreads();

            // ---- reduce partials + RK4 combine (also seeds next stage's z/ya) ----
            if (tid < RB) {
                float k0 = s.part[0][tid][0] + s.part[1][tid][0]
                         + s.part[2][tid][0] + s.part[3][tid][0] + b4g[0];
                float k1 = s.part[0][tid][1] + s.part[1][tid][1]
                         + s.part[2][tid][1] + s.part[3][tid][1] + b4g[1];
                float wg = (e == 0 || e == 3) ? dt * (1.f / 6.f) : dt * (1.f / 3.f);
                float ya0 = s.ya[tid][0] + wg * k0;
                float ya1 = s.ya[tid][1] + wg * k1;
                s.ya[tid][0] = ya0; s.ya[tid][1] = ya1;
                if (e < 3) {
                    float aa = (e == 2) ? dt : dt * 0.5f;
                    s.z[tid][0] = s.y[tid][0] + aa * k0;
                    s.z[tid][1] = s.y[tid][1] + aa * k1;
                } else {
                    s.y[tid][0] = ya0; s.y[tid][1] = ya1;
                    s.z[tid][0] = ya0; s.z[tid][1] = ya1;   // z/ya for next stage = y_next
                    ((float2*)out)[(size_t)(st + 1) * Bn + b0 + tid] =
                        make_float2(ya0, ya1);
                }
            }
            __syncthreads();
        }
    }
}

extern "C" void kernel_launch(void* const* d_in, const int* in_sizes, int n_in,
                              void* d_out, int out_size, void* d_ws, size_t ws_size,
                              hipStream_t stream)
{
    const float* y0 = (const float*)d_in[0];
    const float* tp = (const float*)d_in[1];
    const float* W1 = (const float*)d_in[2];
    const float* b1 = (const float*)d_in[3];
    const float* W2 = (const float*)d_in[4];
    const float* b2 = (const float*)d_in[5];
    const float* W3 = (const float*)d_in[6];
    const float* b3 = (const float*)d_in[7];
    const float* W4 = (const float*)d_in[8];
    const float* b4 = (const float*)d_in[9];
    float* out = (float*)d_out;

    const int Bn = in_sizes[0] / 2;
    const int T  = in_sizes[1];

    uint4* w2A = (uint4*)d_ws;            // 32768 uint4 = 512 KB
    uint4* w3A = w2A + 32768;             // 16384 uint4 = 256 KB
    float* w1p = (float*)(w3A + 16384);   // 1536 floats (scaled W1 pack)
    float* b2s = w1p + 1536;              // 512 floats
    float* b3s = b2s + 512;               // 256 floats

    prep_weights<<<201, 256, 0, stream>>>(W1, b1, W2, b2, W3, b3,
                                          w2A, w3A, w1p, b2s, b3s);
    node_kernel<<<Bn / RB, NTH, 0, stream>>>(y0, tp, W4, b4,
                                             w2A, w3A, w1p, b2s, b3s, out, Bn, T);
}

// Round 13
// 21623.730 us; speedup vs baseline: 1.4869x; 1.4869x over previous
//
#include <hip/hip_runtime.h>
#include <hip/hip_bf16.h>
#include <stdint.h>

// ---------------- types ----------------
using bfrag_t = __attribute__((ext_vector_type(8))) short;   // 8 bf16 (4 VGPRs)
using f32x16  = __attribute__((ext_vector_type(16))) float;  // 32x32 MFMA acc

#define HID  512
#define H3   256
#define RB   128      // batch rows per block
#define NTH  512      // 8 waves
#define KSC  2.885390081777927f   // 2*log2(e): tanh(x) = 1 - 2/(exp2(KSC*x)+1)
// REGISTER CLIFF (R7/R9/R10/R12 all measured): this config = 128 AGPR + 128 VGPR
// = exactly the 256/wave unified budget at 2 waves/SIMD. ANY extra live state or
// tighter launch_bounds spills to scratch in the K-loop -> FETCH/WRITE explosion
// (10 MB -> 17-30 GB) and 20-50% regression. Do not add live registers.

static __device__ __forceinline__ uint32_t bf16_rne(float f) {
    uint32_t u = __float_as_uint(f);
    return (u + 0x7fffu + ((u >> 16) & 1u)) >> 16;
}
static __device__ __forceinline__ uint32_t pk_bf16(float a, float b) {
    union { __hip_bfloat162 h; uint32_t u; } c;
    c.h = __float22bfloat162_rn(make_float2(a, b));   // v_cvt_pk_bf16_f32 on gfx950
    return c.u;
}
static __device__ __forceinline__ float fast_exp2(float x) {
#if __has_builtin(__builtin_amdgcn_exp2f)
    return __builtin_amdgcn_exp2f(x);
#else
    return exp2f(x);
#endif
}
static __device__ __forceinline__ float fast_rcp(float x) {
#if __has_builtin(__builtin_amdgcn_rcpf)
    return __builtin_amdgcn_rcpf(x);
#else
    return 1.0f / x;
#endif
}
// input is PRE-SCALED by KSC (weights/biases scaled in prep)
static __device__ __forceinline__ float ftanh_s(float xs) {
    float e = fast_exp2(xs);
    return 1.0f - 2.0f * fast_rcp(e + 1.0f);
}
static __device__ __forceinline__ bfrag_t frag_of(uint4 v) {
    union { uint4 u; bfrag_t f; } c; c.u = v; return c.f;
}

// ---------------- prep: swizzle W2^T / W3^T (scaled by KSC) into 32x32x16 MFMA
// A-frag order; also emit scaled W1-pack [ck][w0*8|w1*8|b*8] and scaled b2/b3. ----
// A-frag layout (32x32x16 bf16): lane l -> m = l&31, k = kt*16 + (l>>5)*8 + j (j=0..7,
// packed as 4 dwords of (even,odd) bf16 pairs). Index: [(mt32*32 + kt)*64 + l].
__global__ void prep_weights(const float* __restrict__ W1, const float* __restrict__ b1,
                             const float* __restrict__ W2, const float* __restrict__ b2,
                             const float* __restrict__ W3, const float* __restrict__ b3,
                             uint4* __restrict__ o2, uint4* __restrict__ o3,
                             float* __restrict__ w1p, float* __restrict__ b2s,
                             float* __restrict__ b3s)
{
    int id = blockIdx.x * 256 + threadIdx.x;
    if (id < 32768) {                       // W2: 16 mt32 * 32 kt * 64 lanes
        int l = id & 63, kt = (id >> 6) & 31, mt = id >> 11;
        int m = mt * 32 + (l & 31), k0 = kt * 16 + (l >> 5) * 8;
        uint32_t p[4];
        #pragma unroll
        for (int jj = 0; jj < 4; ++jj) {
            float v0 = KSC * W2[(k0 + jj * 2    ) * 512 + m];  // W2^T[m][k] = W2[k][m]
            float v1 = KSC * W2[(k0 + jj * 2 + 1) * 512 + m];
            p[jj] = bf16_rne(v0) | (bf16_rne(v1) << 16);
        }
        o2[id] = make_uint4(p[0], p[1], p[2], p[3]);
    } else if (id < 49152) {                // W3: 8 mt32 * 32 kt * 64 lanes
        int id2 = id - 32768;
        int l = id2 & 63, kt = (id2 >> 6) & 31, mt = id2 >> 11;
        int m = mt * 32 + (l & 31), k0 = kt * 16 + (l >> 5) * 8;
        uint32_t p[4];
        #pragma unroll
        for (int jj = 0; jj < 4; ++jj) {
            float v0 = KSC * W3[(k0 + jj * 2    ) * 256 + m];
            float v1 = KSC * W3[(k0 + jj * 2 + 1) * 256 + m];
            p[jj] = bf16_rne(v0) | (bf16_rne(v1) << 16);
        }
        o3[id2] = make_uint4(p[0], p[1], p[2], p[3]);
    } else if (id < 49152 + 1536) {         // W1 pack: 64 chunks x 24 floats
        int t = id - 49152;
        int ck = t / 24, j = t % 24;
        int f = ck * 8 + (j & 7);
        float v = (j < 8) ? W1[f] : (j < 16) ? W1[512 + f] : b1[f];
        w1p[t] = KSC * v;
    } else if (id < 49152 + 1536 + 512) {
        int i = id - 49152 - 1536; b2s[i] = KSC * b2[i];
    } else if (id < 49152 + 1536 + 512 + 256) {
        int i = id - 49152 - 1536 - 512; b3s[i] = KSC * b3[i];
    }
}

// ---------------- main persistent kernel ----------------
struct SmemT {
    uint4  hbuf[64 * RB];   // 128 KB: h1/h2 (512 feats) or h3 (first 32 chunks)
    float  b2[HID];          // scaled
    float  b3[H3];           // scaled
    float  y [RB][2];
    float  z [RB][2];
    float  ya[RB][2];
    float  part[4][RB][2];   // layer4 partials
};

__global__ __launch_bounds__(NTH, 2) void node_kernel(
    const float* __restrict__ y0, const float* __restrict__ tp,
    const float* __restrict__ W4g, const float* __restrict__ b4g,
    const uint4* __restrict__ w2A, const uint4* __restrict__ w3A,
    const float* __restrict__ w1p, const float* __restrict__ b2s,
    const float* __restrict__ b3s,
    float* __restrict__ out, int Bn, int T)
{
    __shared__ SmemT s;
    const int tid = threadIdx.x;
    const int l   = tid & 63;
    const int w   = tid >> 6;                                  // wave 0..7
    const int wu  = __builtin_amdgcn_readfirstlane(w);         // provably uniform
    const int b0  = blockIdx.x * RB;
    const int ln  = l & 31, lh = l >> 5;

    // stage biases (scaled) to LDS; init y/z/ya; write trajectory[0]
    for (int i = tid; i < HID; i += NTH) s.b2[i] = b2s[i];
    for (int i = tid; i < H3;  i += NTH) s.b3[i] = b3s[i];
    if (tid < RB) {
        float2 v = ((const float2*)y0)[b0 + tid];
        s.y [tid][0] = v.x; s.y [tid][1] = v.y;
        s.z [tid][0] = v.x; s.z [tid][1] = v.y;
        s.ya[tid][0] = v.x; s.ya[tid][1] = v.y;
        ((float2*)out)[b0 + tid] = v;          // trajectory[0] = y0
    }
    __syncthreads();

    const float* w1w = w1p + wu * 8 * 24;      // this wave's 8 chunks (uniform)
    // per-wave weight base pointers: element (mt,kt) at pW[mt*2048 + kt*64]
    const uint4* pW2 = w2A + (wu * 64) * 64 + l;       // mt32 = wu*2 + mt
    const int mg = wu >> 1, ng = wu & 1;
    const uint4* pW3 = w3A + (mg * 64) * 64 + l;       // mt32 = mg*2 + mt

    for (int st = 0; st < T - 1; ++st) {
        float dt = tp[st + 1] - tp[st];

        for (int e = 0; e < 4; ++e) {
            // ---- prefetch L2's first two A-frag pairs (hide L2 latency under L1) ----
            uint4 aC[2], aN[2];
            aC[0] = pW2[0];           aC[1] = pW2[32 * 64];
            aN[0] = pW2[64];          aN[1] = pW2[32 * 64 + 64];

            // ---- layer1: h1 = tanh(z @ W1 + b1); two rows per lane ----
            {
                float zl0 = s.z[l][0],      zl1 = s.z[l][1];
                float zh0 = s.z[64 + l][0], zh1 = s.z[64 + l][1];
                #pragma unroll
                for (int i = 0; i < 8; ++i) {
                    const float* P = w1w + i * 24;   // uniform -> s_load
                    int ck = wu * 8 + i;
                    float xa[8], xb[8];
                    #pragma unroll
                    for (int jj = 0; jj < 8; ++jj) {
                        float wa = P[jj], wb = P[8 + jj], bb = P[16 + jj];
                        xa[jj] = ftanh_s(fmaf(zl0, wa, fmaf(zl1, wb, bb)));
                        xb[jj] = ftanh_s(fmaf(zh0, wa, fmaf(zh1, wb, bb)));
                    }
                    s.hbuf[ck * RB + l] = make_uint4(
                        pk_bf16(xa[0], xa[1]), pk_bf16(xa[2], xa[3]),
                        pk_bf16(xa[4], xa[5]), pk_bf16(xa[6], xa[7]));
                    s.hbuf[ck * RB + 64 + l] = make_uint4(
                        pk_bf16(xb[0], xb[1]), pk_bf16(xb[2], xb[3]),
                        pk_bf16(xb[4], xb[5]), pk_bf16(xb[6], xb[7]));
                }
            }
            __syncthreads();

            // ---- layer2: h2^T = W2^T @ h1^T + b2   M=512, N=128, K=512 (32x32x16) ----
            uint4 a3C[2], a3N[2];
            {
                f32x16 acc[2][4];
                #pragma unroll
                for (int mt = 0; mt < 2; ++mt) {
                    int mb = (wu * 2 + mt) * 32 + 4 * lh;
                    float bv[16];
                    *(float4*)&bv[0]  = *(const float4*)&s.b2[mb];
                    *(float4*)&bv[4]  = *(const float4*)&s.b2[mb + 8];
                    *(float4*)&bv[8]  = *(const float4*)&s.b2[mb + 16];
                    *(float4*)&bv[12] = *(const float4*)&s.b2[mb + 24];
                    f32x16 a;
                    #pragma unroll
                    for (int r = 0; r < 16; ++r) a[r] = bv[r];
                    #pragma unroll
                    for (int nt = 0; nt < 4; ++nt) acc[mt][nt] = a;
                }
                #pragma unroll 2
                for (int kt = 0; kt < 32; ++kt) {
                    uint4 bF[4];
                    #pragma unroll
                    for (int nt = 0; nt < 4; ++nt)
                        bF[nt] = s.hbuf[(kt * 2 + lh) * RB + nt * 32 + ln];
                    int kq = (kt < 30) ? (kt + 2) : 29;      // 2-deep prefetch (clamped)
                    uint4 aM0 = pW2[kq * 64];
                    uint4 aM1 = pW2[32 * 64 + kq * 64];
                    #pragma unroll
                    for (int mt = 0; mt < 2; ++mt)
                        #pragma unroll
                        for (int nt = 0; nt < 4; ++nt)
                            acc[mt][nt] = __builtin_amdgcn_mfma_f32_32x32x16_bf16(
                                frag_of(aC[mt]), frag_of(bF[nt]), acc[mt][nt], 0, 0, 0);
                    aC[0] = aN[0]; aC[1] = aN[1];
                    aN[0] = aM0;   aN[1] = aM1;
                }
                // prefetch L3's first two A-frags (hide latency under epilogue+barrier)
                a3C[0] = pW3[0];      a3C[1] = pW3[32 * 64];
                a3N[0] = pW3[64];     a3N[1] = pW3[32 * 64 + 64];
                __syncthreads();   // all waves done reading h1
                // epilogue: tanh (pre-scaled), pack, overwrite hbuf with h2
                // C/D: col = ln (batch row), row = (r&3) + 8*(r>>2) + 4*lh
                #pragma unroll
                for (int mt = 0; mt < 2; ++mt) {
                    int m0 = (wu * 2 + mt) * 32 + 4 * lh;
                    int hi = lh;                     // (m0>>2)&1
                    #pragma unroll
                    for (int nt = 0; nt < 4; ++nt) {
                        int n = nt * 32 + ln;
                        f32x16 c = acc[mt][nt];
                        #pragma unroll
                        for (int g = 0; g < 4; ++g) {
                            int ck = (m0 + 8 * g) >> 3;
                            uint32_t u0 = pk_bf16(ftanh_s(c[4 * g    ]), ftanh_s(c[4 * g + 1]));
                            uint32_t u1 = pk_bf16(ftanh_s(c[4 * g + 2]), ftanh_s(c[4 * g + 3]));
                            ((uint2*)s.hbuf)[((ck * RB + n) << 1) | hi] = make_uint2(u0, u1);
                        }
                    }
                }
                __syncthreads();
            }

            // ---- layer3: h3^T = W3^T @ h2^T + b3   M=256, N=128, K=512 (32x32x16) ----
            {
                f32x16 acc[2][2];
                #pragma unroll
                for (int mt = 0; mt < 2; ++mt) {
                    int mb = (mg * 2 + mt) * 32 + 4 * lh;
                    float bv[16];
                    *(float4*)&bv[0]  = *(const float4*)&s.b3[mb];
                    *(float4*)&bv[4]  = *(const float4*)&s.b3[mb + 8];
                    *(float4*)&bv[8]  = *(const float4*)&s.b3[mb + 16];
                    *(float4*)&bv[12] = *(const float4*)&s.b3[mb + 24];
                    f32x16 a;
                    #pragma unroll
                    for (int r = 0; r < 16; ++r) a[r] = bv[r];
                    #pragma unroll
                    for (int nt = 0; nt < 2; ++nt) acc[mt][nt] = a;
                }
                #pragma unroll 2
                for (int kt = 0; kt < 32; ++kt) {
                    uint4 bF[2];
                    #pragma unroll
                    for (int nt = 0; nt < 2; ++nt)
                        bF[nt] = s.hbuf[(kt * 2 + lh) * RB + ng * 64 + nt * 32 + ln];
                    int kq = (kt < 30) ? (kt + 2) : 29;
                    uint4 aM0 = pW3[kq * 64];
                    uint4 aM1 = pW3[32 * 64 + kq * 64];
                    #pragma unroll
                    for (int mt = 0; mt < 2; ++mt)
                        #pragma unroll
                        for (int nt = 0; nt < 2; ++nt)
                            acc[mt][nt] = __builtin_amdgcn_mfma_f32_32x32x16_bf16(
                                frag_of(a3C[mt]), frag_of(bF[nt]), acc[mt][nt], 0, 0, 0);
                    a3C[0] = a3N[0]; a3C[1] = a3N[1];
                    a3N[0] = aM0;    a3N[1] = aM1;
                }
                __syncthreads();   // all waves done reading h2
                #pragma unroll
                for (int mt = 0; mt < 2; ++mt) {
                    int m0 = (mg * 2 + mt) * 32 + 4 * lh;   // feature 0..255 -> ck 0..31
                    int hi = lh;
                    #pragma unroll
                    for (int nt = 0; nt < 2; ++nt) {
                        int n = ng * 64 + nt * 32 + ln;
                        f32x16 c = acc[mt][nt];
                        #pragma unroll
                        for (int g = 0; g < 4; ++g) {
                            int ck = (m0 + 8 * g) >> 3;
                            uint32_t u0 = pk_bf16(ftanh_s(c[4 * g    ]), ftanh_s(c[4 * g + 1]));
                            uint32_t u1 = pk_bf16(ftanh_s(c[4 * g + 2]), ftanh_s(c[4 * g + 3]));
                            ((uint2*)s.hbuf)[((ck * RB + n) << 1) | hi] = make_uint2(u0, u1);
                        }
                    }
                }
                __syncthreads();
            }

            // ---- layer4 partials: contiguous-row reads, uniform W4 s_loads ----
            {
                int r  = tid & 127;                      // = l + 64*(w&1): contiguous
                int qq = __builtin_amdgcn_readfirstlane(tid >> 7);  // 0..3 uniform
                float a0 = 0.f, a1 = 0.f;
                #pragma unroll
                for (int j = 0; j < 8; ++j) {
                    int ck = qq * 8 + j;
                    uint4 hv = s.hbuf[ck * RB + r];
                    const uint32_t* pu = (const uint32_t*)&hv;
                    #pragma unroll
                    for (int jj = 0; jj < 4; ++jj) {
                        uint32_t uu = pu[jj];
                        float h0 = __uint_as_float(uu << 16);
                        float h1 = __uint_as_float(uu & 0xffff0000u);
                        int f = ck * 8 + jj * 2;                     // uniform
                        a0 = fmaf(h0, W4g[f * 2],     fmaf(h1, W4g[f * 2 + 2], a0));
                        a1 = fmaf(h0, W4g[f * 2 + 1], fmaf(h1, W4g[f * 2 + 3], a1));
                    }
                }
                s.part[qq][r][0] = a0; s.part[qq][r][1] = a1;
            }
            __syncthreads();

            // ---- reduce partials + RK4 combine (also seeds next stage's z/ya) ----
            if (tid < RB) {
                float k0 = s.part[0][tid][0] + s.part[1][tid][0]
                         + s.part[2][tid][0] + s.part[3][tid][0] + b4g[0];
                float k1 = s.part[0][tid][1] + s.part[1][tid][1]
                         + s.part[2][tid][1] + s.part[3][tid][1] + b4g[1];
                float wg = (e == 0 || e == 3) ? dt * (1.f / 6.f) : dt * (1.f / 3.f);
                float ya0 = s.ya[tid][0] + wg * k0;
                float ya1 = s.ya[tid][1] + wg * k1;
                s.ya[tid][0] = ya0; s.ya[tid][1] = ya1;
                if (e < 3) {
                    float aa = (e == 2) ? dt : dt * 0.5f;
                    s.z[tid][0] = s.y[tid][0] + aa * k0;
                    s.z[tid][1] = s.y[tid][1] + aa * k1;
                } else {
                    s.y[tid][0] = ya0; s.y[tid][1] = ya1;
                    s.z[tid][0] = ya0; s.z[tid][1] = ya1;   // z/ya for next stage = y_next
                    ((float2*)out)[(size_t)(st + 1) * Bn + b0 + tid] =
                        make_float2(ya0, ya1);
                }
            }
            __syncthreads();
        }
    }
}

extern "C" void kernel_launch(void* const* d_in, const int* in_sizes, int n_in,
                              void* d_out, int out_size, void* d_ws, size_t ws_size,
                              hipStream_t stream)
{
    const float* y0 = (const float*)d_in[0];
    const float* tp = (const float*)d_in[1];
    const float* W1 = (const float*)d_in[2];
    const float* b1 = (const float*)d_in[3];
    const float* W2 = (const float*)d_in[4];
    const float* b2 = (const float*)d_in[5];
    const float* W3 = (const float*)d_in[6];
    const float* b3 = (const float*)d_in[7];
    const float* W4 = (const float*)d_in[8];
    const float* b4 = (const float*)d_in[9];
    float* out = (float*)d_out;

    const int Bn = in_sizes[0] / 2;
    const int T  = in_sizes[1];

    uint4* w2A = (uint4*)d_ws;            // 32768 uint4 = 512 KB
    uint4* w3A = w2A + 32768;             // 16384 uint4 = 256 KB
    float* w1p = (float*)(w3A + 16384);   // 1536 floats (scaled W1 pack)
    float* b2s = w1p + 1536;              // 512 floats
    float* b3s = b2s + 512;               // 256 floats

    prep_weights<<<201, 256, 0, stream>>>(W1, b1, W2, b2, W3, b3,
                                          w2A, w3A, w1p, b2s, b3s);
    node_kernel<<<Bn / RB, NTH, 0, stream>>>(y0, tp, W4, b4,
                                             w2A, w3A, w1p, b2s, b3s, out, Bn, T);
}